// Round 5
// baseline (383.470 us; speedup 1.0000x reference)
//
#include <hip/hip_runtime.h>
#include <math.h>

// Problem constants
#define BSZ 4
#define CCH 8192
#define HW  1024               // H*W = 32*32
#define DEMB 256
#define NPOS (BSZ*HW)          // 4096 spatial positions
#define QSIZE (BSZ*DEMB*HW)    // 1048576 floats (quantized)
#define KLOFF QSIZE            // kl scalar float offset in out
#define OHOFF (QSIZE+1)        // one_hot start (NOT 16B aligned)
#define OHSZ  ((size_t)BSZ*CCH*HW)  // 33554432

typedef float vf4 __attribute__((ext_vector_type(4)));
typedef unsigned long long u64;

// ws layout (64 KB total):
//   pk  = u64[NPOS]   packed (monotonic(best) << 32) | (CCH-1-idx)
//   ps  = f32[NPOS]   sum of exp(x) over channels
//   psx = f32[NPOS]   sum of x over channels
// Merged via device-scope atomics. atomicMax on the packed key is
// order-independent and bit-exact (incl. first-occurrence tie-break via
// CCH-1-idx; finite floats always map to key>0 so the 0-init never wins);
// atomicAdd ordering only perturbs the kl scalar (~1e-6 rel).
// The harness re-poisons ws between iterations -> vq_init is mandatory
// (poison bytes would be absorbing for atomicMax).

// Init: zero the 64 KB merge buffer. 16 blocks x 256 threads x 16 B.
__global__ __launch_bounds__(256) void vq_init(float* __restrict__ ws) {
    int i = blockIdx.x * 256 + threadIdx.x;
    ((vf4*)ws)[i] = (vf4)(0.f);
}

// Phase 1: VERIFIED round-0 body (85 us): block = (b, chunk of CPB channels,
// all 1024 hw). 256 threads; thread t owns hw positions 4t..4t+3 (vf4).
// Streams x/g contiguously with batched (UN=16) NT loads, fuses the one_hot
// zeroing via shifted-aligned NT vf4 stores (out[QSIZE+n..n+3]; the flat=0
// store also zeros the kl scalar). ONLY the tail differs from round 0:
// partials merge via atomics instead of a 16.8 MB ws round-trip.
template<int CPB>
__global__ __launch_bounds__(256) void vq_phase1(const float* __restrict__ x,
                                                 const float* __restrict__ g,
                                                 float* __restrict__ out,
                                                 float* __restrict__ ws) {
    constexpr int NCH = CCH / CPB;
    constexpr int UN  = 16;
    int bid = blockIdx.x;
    int q = bid % NCH;
    int b = bid / NCH;
    int t = threadIdx.x;
    int c0 = q * CPB;
    size_t base = ((size_t)(b * CCH + c0)) * HW + 4 * t;

    float best[4]; int bidx[4]; float s[4], sx[4];
#pragma unroll
    for (int j = 0; j < 4; j++) { best[j] = -INFINITY; bidx[j] = 0; s[j] = 0.f; sx[j] = 0.f; }

    const vf4 z4 = (vf4)(0.f);
    for (int cg = 0; cg < CPB / UN; cg++) {
        size_t a0 = base + (size_t)cg * UN * HW;
        vf4 xv[UN], gv[UN];
#pragma unroll
        for (int u = 0; u < UN; u++)
            xv[u] = __builtin_nontemporal_load((const vf4*)(x + a0 + (size_t)u * HW));
#pragma unroll
        for (int u = 0; u < UN; u++)
            gv[u] = __builtin_nontemporal_load((const vf4*)(g + a0 + (size_t)u * HW));
#pragma unroll
        for (int u = 0; u < UN; u++)
            __builtin_nontemporal_store(z4, (vf4*)(out + QSIZE + a0 + (size_t)u * HW));
#pragma unroll
        for (int u = 0; u < UN; u++) {
            int cc = c0 + cg * UN + u;
#pragma unroll
            for (int j = 0; j < 4; j++) {
                float xa = xv[u][j];
                float z = xa + gv[u][j];
                if (z > best[j]) { best[j] = z; bidx[j] = cc; }
                s[j]  += __expf(xa);
                sx[j] += xa;
            }
        }
    }

    // single element not covered by the shifted tiling: one_hot[last]
    if (b == BSZ - 1 && q == NCH - 1 && t == 255)
        out[QSIZE + OHSZ] = 0.f;

    // merge partials directly via atomics (no 16.8 MB ws round-trip).
    u64*   pk  = (u64*)ws;
    float* ps  = ws + 2 * (size_t)NPOS;
    float* psx = ws + 3 * (size_t)NPOS;
    int p0 = b * HW + 4 * t;
#pragma unroll
    for (int j = 0; j < 4; j++) {
        unsigned ub  = __float_as_uint(best[j]);
        unsigned key = (ub & 0x80000000u) ? ~ub : (ub | 0x80000000u);
        u64 v = ((u64)key << 32) | (unsigned)(CCH - 1 - bidx[j]);
        atomicMax(&pk[p0 + j], v);      // order-independent argmax, min-idx ties
        atomicAdd(&ps[p0 + j], s[j]);
        atomicAdd(&psx[p0 + j], sx[j]);
    }
}

// Phase 2 (finalize, now tiny): grid NPOS/16 blocks x 256 threads.
// (a) decode packed argmax, write one_hot 1.0s + KL atomic, (b) load the 16
// selected emb rows coalesced into LDS, transpose, and write the quantized
// tile with per-thread 64B float4 runs (verified round-0 gather/write code).
__global__ __launch_bounds__(256) void vq_phase2(const float* __restrict__ emb,
                                                 float* __restrict__ out,
                                                 const float* __restrict__ ws) {
    constexpr int TP = 272;            // tile pitch (256+16)
    const u64*   pk  = (const u64*)ws;
    const float* ps  = ws + 2 * (size_t)NPOS;
    const float* psx = ws + 3 * (size_t)NPOS;

    __shared__ int   smi[16];
    __shared__ float tsum[16];
    __shared__ float tile[16 * TP];

    int tid  = threadIdx.x;
    int pos0 = blockIdx.x * 16;

    if (tid < 16) {
        int pos = pos0 + tid;
        u64 v = pk[pos];
        int mi = (CCH - 1) - (int)(unsigned)(v & 0xFFFFFFFFu);
        smi[tid] = mi;
        int bb = pos >> 10;
        int hw = pos & (HW - 1);
        out[OHOFF + ((size_t)(bb * CCH + mi)) * HW + hw] = 1.0f;

        const float logt = -9.0109131783f;  // log(1/8192)
        tsum[tid] = logt + __logf(ps[pos]) - psx[pos] * (1.0f / (float)CCH);
    }
    __syncthreads();
    if (tid == 0) {
        float tt = 0.f;
        for (int p = 0; p < 16; p++) tt += tsum[p];
        atomicAdd(out + KLOFF, (0.25f / (float)BSZ) * tt);
    }

    // gather emb rows -> LDS (coalesced float4 loads, 4 rows per pass)
    int rr = tid >> 6;          // 0..3
    int c4 = (tid & 63) * 4;    // 0..252
#pragma unroll
    for (int rep = 0; rep < 4; rep++) {
        int r = rep * 4 + rr;
        float4 v = *(const float4*)(emb + (size_t)smi[r] * DEMB + c4);
        *(float4*)(tile + r * TP + c4) = v;
    }
    __syncthreads();

    // write quantized: thread d=tid owns a 64B run (16 hw) per 4-row group
    int b = pos0 >> 10;
    int hw0 = pos0 & (HW - 1);
    int d = tid;
    size_t obase = (((size_t)(b * DEMB + d)) << 10) + hw0;
#pragma unroll
    for (int k = 0; k < 4; k++) {
        float4 v;
        v.x = tile[(4 * k + 0) * TP + d];
        v.y = tile[(4 * k + 1) * TP + d];
        v.z = tile[(4 * k + 2) * TP + d];
        v.w = tile[(4 * k + 3) * TP + d];
        *(float4*)(out + obase + 4 * k) = v;
    }
}

extern "C" void kernel_launch(void* const* d_in, const int* in_sizes, int n_in,
                              void* d_out, int out_size, void* d_ws, size_t ws_size,
                              hipStream_t stream) {
    (void)in_sizes; (void)n_in; (void)out_size; (void)ws_size;
    const float* x   = (const float*)d_in[0];
    const float* emb = (const float*)d_in[1];
    const float* g   = (const float*)d_in[2];
    float* out = (float*)d_out;
    float* ws  = (float*)d_ws;

    // zero the 64 KB atomic-merge buffer with a plain kernel launch
    // (NO hipMemsetAsync inside kernel_launch: graph-capture tripwire)
    vq_init<<<dim3(16), dim3(256), 0, stream>>>(ws);

    // CPB=32 -> 1024 blocks, vf4 per-thread (verified 85us body)
    vq_phase1<32><<<dim3(BSZ * (CCH / 32)), dim3(256), 0, stream>>>(x, g, out, ws);
    vq_phase2<<<dim3(NPOS / 16), dim3(256), 0, stream>>>(emb, out, ws);
}

// Round 6
// 325.122 us; speedup vs baseline: 1.1795x; 1.1795x over previous
//
#include <hip/hip_runtime.h>
#include <math.h>

// Problem constants
#define BSZ 4
#define CCH 8192
#define HW  1024               // H*W = 32*32
#define DEMB 256
#define NPOS (BSZ*HW)          // 4096 spatial positions
#define QSIZE (BSZ*DEMB*HW)    // 1048576 floats (quantized)
#define KLOFF QSIZE            // kl scalar float offset in out
#define OHOFF (QSIZE+1)        // one_hot start (NOT 16B aligned)
#define OHSZ  ((size_t)BSZ*CCH*HW)  // 33554432

typedef float vf4 __attribute__((ext_vector_type(4)));

// Phase 1: VERIFIED 85us body (round 0). Block = (b, chunk of CPB channels,
// all 1024 hw). 256 threads; thread t owns hw positions 4t..4t+3 (vf4).
// Streams x/g contiguously with batched (UN=16) NT loads, fuses the one_hot
// zeroing via shifted-aligned NT vf4 stores (out[QSIZE+n..n+3]; the flat=0
// store also zeros the kl scalar). ONLY delta vs round 0: ws partials are
// AoS float4 {best, idx_bits, s, sx} per (chunk,pos) so phase2 reads one
// vectorized float4 instead of 4 scattered scalar loads. Bit-exact.
template<int CPB>
__global__ __launch_bounds__(256) void vq_phase1(const float* __restrict__ x,
                                                 const float* __restrict__ g,
                                                 float* __restrict__ out,
                                                 float* __restrict__ ws) {
    constexpr int NCH = CCH / CPB;
    constexpr int UN  = 16;
    int bid = blockIdx.x;
    int q = bid % NCH;
    int b = bid / NCH;
    int t = threadIdx.x;
    int c0 = q * CPB;
    size_t base = ((size_t)(b * CCH + c0)) * HW + 4 * t;

    float best[4]; int bidx[4]; float s[4], sx[4];
#pragma unroll
    for (int j = 0; j < 4; j++) { best[j] = -INFINITY; bidx[j] = 0; s[j] = 0.f; sx[j] = 0.f; }

    const vf4 z4 = (vf4)(0.f);
    for (int cg = 0; cg < CPB / UN; cg++) {
        size_t a0 = base + (size_t)cg * UN * HW;
        vf4 xv[UN], gv[UN];
#pragma unroll
        for (int u = 0; u < UN; u++)
            xv[u] = __builtin_nontemporal_load((const vf4*)(x + a0 + (size_t)u * HW));
#pragma unroll
        for (int u = 0; u < UN; u++)
            gv[u] = __builtin_nontemporal_load((const vf4*)(g + a0 + (size_t)u * HW));
#pragma unroll
        for (int u = 0; u < UN; u++)
            __builtin_nontemporal_store(z4, (vf4*)(out + QSIZE + a0 + (size_t)u * HW));
#pragma unroll
        for (int u = 0; u < UN; u++) {
            int cc = c0 + cg * UN + u;
#pragma unroll
            for (int j = 0; j < 4; j++) {
                float xa = xv[u][j];
                float z = xa + gv[u][j];
                if (z > best[j]) { best[j] = z; bidx[j] = cc; }
                s[j]  += __expf(xa);
                sx[j] += xa;
            }
        }
    }

    // single element not covered by the shifted tiling: one_hot[last]
    if (b == BSZ - 1 && q == NCH - 1 && t == 255)
        out[QSIZE + OHSZ] = 0.f;

    // AoS partials: one float4 {best, idx_bits, s, sx} per (q,pos).
    // Thread writes 4 consecutive float4s = 64B contiguous run.
    float4* waos = (float4*)ws;
    int o = q * NPOS + b * HW + 4 * t;
#pragma unroll
    for (int j = 0; j < 4; j++)
        waos[o + j] = make_float4(best[j], __int_as_float(bidx[j]), s[j], sx[j]);
}

// Phase 2 (fused finalize): grid NPOS/16 blocks x 256 threads.
// (a) merge NCH chunk-partials per position (thread = pl 0..15 x qg 0..15,
//     one float4 load per chunk, LDS merge), (b) write one_hot 1.0s + KL
//     atomic, (c) load the 16 selected emb rows coalesced into LDS,
//     transpose, and write the quantized tile with per-thread 64B runs.
template<int CPB>
__global__ __launch_bounds__(256) void vq_phase2(const float* __restrict__ emb,
                                                 float* __restrict__ out,
                                                 float* __restrict__ ws) {
    constexpr int NCH = CCH / CPB;
    constexpr int QPT = NCH / 16;
    constexpr int TP  = 272;           // tile pitch (256+16)
    const float4* waos = (const float4*)ws;

    int tid = threadIdx.x;
    int pl = tid & 15;
    int qg = tid >> 4;
    int pos0 = blockIdx.x * 16;
    int pos = pos0 + pl;

    float fb = -INFINITY; int fi = 0;
    float fs = 0.f, fsx = 0.f;
    for (int i = 0; i < QPT; i++) {
        int q = qg * QPT + i;
        float4 v4 = waos[q * NPOS + pos];
        float v = v4.x; int ci = __float_as_int(v4.y);
        if (v > fb || (v == fb && ci < fi)) { fb = v; fi = ci; }
        fs  += v4.z;
        fsx += v4.w;
    }

    __shared__ float l_b [16][17];
    __shared__ int   l_i [16][17];
    __shared__ float l_s [16][17];
    __shared__ float l_sx[16][17];
    __shared__ float tsum[16];
    __shared__ int   smi[16];
    __shared__ float tile[16 * TP];
    l_b [qg][pl] = fb;
    l_i [qg][pl] = fi;
    l_s [qg][pl] = fs;
    l_sx[qg][pl] = fsx;
    __syncthreads();

    if (tid < 16) {
        int p = tid;
        float mb = l_b[0][p]; int mi = l_i[0][p];
        float ms = l_s[0][p], msx = l_sx[0][p];
        for (int qq = 1; qq < 16; qq++) {
            float v = l_b[qq][p]; int ci = l_i[qq][p];
            if (v > mb || (v == mb && ci < mi)) { mb = v; mi = ci; }
            ms  += l_s[qq][p];
            msx += l_sx[qq][p];
        }
        int mypos = pos0 + p;
        smi[p] = mi;
        int bb = mypos >> 10;
        int hw = mypos & (HW - 1);
        out[OHOFF + ((size_t)(bb * CCH + mi)) * HW + hw] = 1.0f;

        const float logt = -9.0109131783f;  // log(1/8192)
        tsum[p] = logt + __logf(ms) - msx * (1.0f / (float)CCH);
    }
    __syncthreads();
    if (tid == 0) {
        float tt = 0.f;
        for (int p = 0; p < 16; p++) tt += tsum[p];
        atomicAdd(out + KLOFF, (0.25f / (float)BSZ) * tt);
    }

    // (c) gather emb rows -> LDS (coalesced float4 loads, 4 rows per pass)
    int rr = tid >> 6;          // 0..3
    int c4 = (tid & 63) * 4;    // 0..252
#pragma unroll
    for (int rep = 0; rep < 4; rep++) {
        int r = rep * 4 + rr;
        float4 v = *(const float4*)(emb + (size_t)smi[r] * DEMB + c4);
        *(float4*)(tile + r * TP + c4) = v;
    }
    __syncthreads();

    // write quantized: thread d=tid owns a 64B run (16 hw) per 4-row group
    int b = pos0 >> 10;
    int hw0 = pos0 & (HW - 1);
    int d = tid;
    size_t obase = (((size_t)(b * DEMB + d)) << 10) + hw0;
#pragma unroll
    for (int k = 0; k < 4; k++) {
        float4 v;
        v.x = tile[(4 * k + 0) * TP + d];
        v.y = tile[(4 * k + 1) * TP + d];
        v.z = tile[(4 * k + 2) * TP + d];
        v.w = tile[(4 * k + 3) * TP + d];
        *(float4*)(out + obase + 4 * k) = v;
    }
}

template<int CPB>
static void launch_all(const float* x, const float* emb, const float* g,
                       float* out, float* ws, hipStream_t stream) {
    constexpr int NCH = CCH / CPB;
    vq_phase1<CPB><<<dim3(BSZ * NCH), dim3(256), 0, stream>>>(x, g, out, ws);
    vq_phase2<CPB><<<dim3(NPOS / 16), dim3(256), 0, stream>>>(emb, out, ws);
}

extern "C" void kernel_launch(void* const* d_in, const int* in_sizes, int n_in,
                              void* d_out, int out_size, void* d_ws, size_t ws_size,
                              hipStream_t stream) {
    (void)in_sizes; (void)n_in; (void)out_size;
    const float* x   = (const float*)d_in[0];
    const float* emb = (const float*)d_in[1];
    const float* g   = (const float*)d_in[2];
    float* out = (float*)d_out;
    float* ws  = (float*)d_ws;

    // ws bytes needed: CPB=32 -> 16*(4096*256) ~= 16.8MB; CPB=64 ~= 8.4MB
    if (ws_size >= (size_t)16 * ((size_t)NPOS * (CCH / 32))) {
        launch_all<32>(x, emb, g, out, ws, stream);   // 1024 blocks
    } else {
        launch_all<64>(x, emb, g, out, ws, stream);   // 512 blocks
    }
}